// Round 1
// baseline (200.239 us; speedup 1.0000x reference)
//
#include <hip/hip_runtime.h>
#include <hip/hip_bf16.h>

#define BB    4
#define NN    16384
#define DD    128
#define HH    8
#define DHH   64
#define INNER 512

typedef __attribute__((ext_vector_type(8))) short bf16x8;
typedef __attribute__((ext_vector_type(4))) float f32x4;

#define MFMA(a, b, c) __builtin_amdgcn_mfma_f32_16x16x32_bf16((a), (b), (c), 0, 0, 0)

// fp32 -> bf16 round-to-nearest-even
__device__ __forceinline__ short f2bf(float x) {
    union { float f; unsigned u; } v; v.f = x;
    unsigned u = v.u;
    u += 0x7fffu + ((u >> 16) & 1u);
    return (short)(u >> 16);
}

// 8 consecutive floats at p -> bf16x8 (A-row / B-row fragment)
__device__ __forceinline__ bf16x8 load_row8(const float* __restrict__ p) {
    f32x4 a = *(const f32x4*)p;
    f32x4 b = *(const f32x4*)(p + 4);
    bf16x8 r;
    r[0] = f2bf(a[0]); r[1] = f2bf(a[1]); r[2] = f2bf(a[2]); r[3] = f2bf(a[3]);
    r[4] = f2bf(b[0]); r[5] = f2bf(b[1]); r[6] = f2bf(b[2]); r[7] = f2bf(b[3]);
    return r;
}

// 8 floats strided by `stride` elements -> bf16x8 (column fragment)
__device__ __forceinline__ bf16x8 load_col8(const float* __restrict__ p, int stride) {
    bf16x8 r;
#pragma unroll
    for (int j = 0; j < 8; ++j) r[j] = f2bf(p[(size_t)j * stride]);
    return r;
}

// ---------------------------------------------------------------------------
// K1: partial S[b] = keys[b]^T @ values[b] over a chunk of rows.
// Grid: BB*PC blocks, 512 threads (8 waves). Wave w owns m-tile w (d rows
// 16w..16w+15) x all 8 e-tiles. Direct global fragment loads (strided scalar),
// fp32 MFMA accumulate, partial written to ws.
// ---------------------------------------------------------------------------
__global__ __launch_bounds__(512) void k1_partialS(
        const float* __restrict__ keys, const float* __restrict__ vals,
        float* __restrict__ partial, int PC, int rows) {
    const int b     = blockIdx.x / PC;
    const int chunk = blockIdx.x % PC;
    const int r0    = chunk * rows;
    const int lane  = threadIdx.x & 63;
    const int w     = threadIdx.x >> 6;   // 0..7
    const int ml    = lane & 15;
    const int quad  = lane >> 4;

    const float* kbase = keys + (size_t)b * NN * DD;
    const float* vbase = vals + (size_t)b * NN * DD;

    f32x4 acc[8];
#pragma unroll
    for (int t = 0; t < 8; ++t) acc[t] = (f32x4){0.f, 0.f, 0.f, 0.f};

    for (int n0 = r0; n0 < r0 + rows; n0 += 32) {
        const int nbase = n0 + quad * 8;
        // A = K^T: A[m=d][k=n] = K[n][d]; lane holds d = 16w+ml, k = nbase+j
        const int d = w * 16 + ml;
        bf16x8 afrag = load_col8(kbase + (size_t)nbase * DD + d, DD);
#pragma unroll
        for (int t = 0; t < 8; ++t) {
            const int e = t * 16 + ml;
            bf16x8 bfrag = load_col8(vbase + (size_t)nbase * DD + e, DD);
            acc[t] = MFMA(afrag, bfrag, acc[t]);
        }
    }
    // C layout: row = 16w + quad*4 + r, col = 16t + ml
    float* outp = partial + (size_t)blockIdx.x * DD * DD;
#pragma unroll
    for (int t = 0; t < 8; ++t) {
        const int col = t * 16 + ml;
#pragma unroll
        for (int r = 0; r < 4; ++r)
            outp[(size_t)(w * 16 + quad * 4 + r) * DD + col] = acc[t][r];
    }
}

// ---------------------------------------------------------------------------
// K2: S[b] = sum of PC partials; also zero G (atomic target for K3).
// Grid: 64 blocks x 256 threads, one float4 of (b,i) per thread.
// ---------------------------------------------------------------------------
__global__ __launch_bounds__(256) void k2_reduce(
        const float* __restrict__ partial, float* __restrict__ S,
        float* __restrict__ G, int PC) {
    const int t  = blockIdx.x * 256 + threadIdx.x;  // 0..16383
    const int b  = t >> 12;
    const int i4 = (t & 4095) * 4;
    f32x4 s = (f32x4){0.f, 0.f, 0.f, 0.f};
    const float* p = partial + ((size_t)b * PC) * DD * DD + i4;
    for (int c = 0; c < PC; ++c)
        s += *(const f32x4*)(p + (size_t)c * DD * DD);
    *(f32x4*)(S + (size_t)b * DD * DD + i4) = s;
    *(f32x4*)(G + (size_t)b * DD * DD + i4) = (f32x4){0.f, 0.f, 0.f, 0.f};
}

// ---------------------------------------------------------------------------
// K3: middle chain per (b,h):
//   T1 = Wk_h @ S[b]          (64x128, K=128)
//   dots = T1 @ Wk_h^T        (64x64,  K=128)
//   T2 = Wq_h^T @ dots        (128x64, K=64)
//   C3 = T2 @ Wo_h^T          (128x128,K=64)  -> atomicAdd into G[b]
// Weights/S read straight from global (L2-hot); intermediates via LDS in
// operand layouts. Pitches 136/72 keep ds_read_b128 16B-aligned, <=2-way banks.
// ---------------------------------------------------------------------------
__global__ __launch_bounds__(256) void k3_middle(
        const float* __restrict__ S, const float* __restrict__ Wq,
        const float* __restrict__ Wk, const float* __restrict__ Wo,
        float* __restrict__ G) {
    const int b    = blockIdx.x >> 3;
    const int h    = blockIdx.x & 7;
    const int lane = threadIdx.x & 63;
    const int w    = threadIdx.x >> 6;   // 0..3
    const int ml   = lane & 15;
    const int quad = lane >> 4;

    __shared__ short lds[22528];
    short* T1 = lds;            // [64][136]  A-layout rows d, cols c'
    short* dT = lds + 8704;     // [64][72]   dots^T: [e][d] (B-layout for T2)
    short* T2 = lds + 13312;    // [128][72]  A-layout rows c', cols e

    const float* Sb  = S  + (size_t)b * DD * DD;
    const float* Wkh = Wk + (size_t)h * DHH * DD;   // Wk[(h*64+d)*128 + c]
    const float* Wqh = Wq + (size_t)h * DHH * DD;

    // s1: T1 = Wk_h @ S[b].  wave w -> m-tile w (d rows 16w..), 8 n-tiles.
    {
        f32x4 acc[8];
#pragma unroll
        for (int t = 0; t < 8; ++t) acc[t] = (f32x4){0.f, 0.f, 0.f, 0.f};
#pragma unroll
        for (int kc = 0; kc < 4; ++kc) {
            const int c0 = kc * 32 + quad * 8;
            bf16x8 a = load_row8(Wkh + (size_t)(w * 16 + ml) * DD + c0);
#pragma unroll
            for (int t = 0; t < 8; ++t) {
                // B[k=c][n=c'] = S[c][c']: column of S, stride 128
                bf16x8 bf = load_col8(Sb + (size_t)c0 * DD + t * 16 + ml, DD);
                acc[t] = MFMA(a, bf, acc[t]);
            }
        }
#pragma unroll
        for (int t = 0; t < 8; ++t)
#pragma unroll
            for (int r = 0; r < 4; ++r)
                T1[(w * 16 + quad * 4 + r) * 136 + t * 16 + ml] = f2bf(acc[t][r]);
    }
    __syncthreads();

    // s2: dots = T1 @ Wk_h^T.  wave w -> m-tile w, 4 n-tiles.
    {
        f32x4 acc[4];
#pragma unroll
        for (int t = 0; t < 4; ++t) acc[t] = (f32x4){0.f, 0.f, 0.f, 0.f};
#pragma unroll
        for (int kc = 0; kc < 4; ++kc) {
            const int c0 = kc * 32 + quad * 8;
            bf16x8 a = *(const bf16x8*)&T1[(w * 16 + ml) * 136 + c0];
#pragma unroll
            for (int t = 0; t < 4; ++t) {
                // B[k=c'][n=e] = Wk_h[e][c'] : row of Wk, contiguous
                bf16x8 bf = load_row8(Wkh + (size_t)(t * 16 + ml) * DD + c0);
                acc[t] = MFMA(a, bf, acc[t]);
            }
        }
        // store transposed: dT[e][d]
#pragma unroll
        for (int t = 0; t < 4; ++t)
#pragma unroll
            for (int r = 0; r < 4; ++r)
                dT[(t * 16 + ml) * 72 + w * 16 + quad * 4 + r] = f2bf(acc[t][r]);
    }
    __syncthreads();

    // s3: T2 = Wq_h^T @ dots.  wave w -> m-tiles 2w,2w+1; 4 n-tiles; kc 0..1.
    {
        f32x4 acc[2][4];
#pragma unroll
        for (int i = 0; i < 2; ++i)
#pragma unroll
            for (int t = 0; t < 4; ++t) acc[i][t] = (f32x4){0.f, 0.f, 0.f, 0.f};
#pragma unroll
        for (int kc = 0; kc < 2; ++kc) {
            const int d0 = kc * 32 + quad * 8;
            bf16x8 a[2];
#pragma unroll
            for (int i = 0; i < 2; ++i) {
                const int cp = (2 * w + i) * 16 + ml;  // m = c'
                // A[m=c'][k=d] = Wq[(h64+d)][c'] : column, stride 128
                a[i] = load_col8(Wqh + (size_t)d0 * DD + cp, DD);
            }
#pragma unroll
            for (int t = 0; t < 4; ++t) {
                bf16x8 bf = *(const bf16x8*)&dT[(t * 16 + ml) * 72 + d0];
                acc[0][t] = MFMA(a[0], bf, acc[0][t]);
                acc[1][t] = MFMA(a[1], bf, acc[1][t]);
            }
        }
#pragma unroll
        for (int i = 0; i < 2; ++i)
#pragma unroll
            for (int t = 0; t < 4; ++t)
#pragma unroll
                for (int r = 0; r < 4; ++r)
                    T2[((2 * w + i) * 16 + quad * 4 + r) * 72 + t * 16 + ml] =
                        f2bf(acc[i][t][r]);
    }
    __syncthreads();

    // s4: C3 = T2 @ Wo_h^T -> atomicAdd G[b].  2 m-tiles, 8 n-tiles, kc 0..1.
    {
        f32x4 acc[2][8];
#pragma unroll
        for (int i = 0; i < 2; ++i)
#pragma unroll
            for (int t = 0; t < 8; ++t) acc[i][t] = (f32x4){0.f, 0.f, 0.f, 0.f};
#pragma unroll
        for (int kc = 0; kc < 2; ++kc) {
            const int e0 = kc * 32 + quad * 8;
            bf16x8 a[2];
#pragma unroll
            for (int i = 0; i < 2; ++i)
                a[i] = *(const bf16x8*)&T2[((2 * w + i) * 16 + ml) * 72 + e0];
#pragma unroll
            for (int t = 0; t < 8; ++t) {
                // B[k=e][n=c] = Wo[c][h64+e] : row of Wo, contiguous
                bf16x8 bf = load_row8(Wo + (size_t)(t * 16 + ml) * INNER + h * DHH + e0);
                acc[0][t] = MFMA(a[0], bf, acc[0][t]);
                acc[1][t] = MFMA(a[1], bf, acc[1][t]);
            }
        }
        float* Gb = G + (size_t)b * DD * DD;
#pragma unroll
        for (int i = 0; i < 2; ++i)
#pragma unroll
            for (int t = 0; t < 8; ++t)
#pragma unroll
                for (int r = 0; r < 4; ++r)
                    atomicAdd(&Gb[((2 * w + i) * 16 + quad * 4 + r) * DD + t * 16 + ml],
                              acc[i][t][r]);
    }
}

// ---------------------------------------------------------------------------
// K4: out[b] = queries[b] @ (G[b]/N) + bo.
// Grid: 512 blocks x 256 threads; block covers 128 rows. G staged to LDS
// transposed+scaled (1/N = 2^-14 exact). A-frags direct from global.
// ---------------------------------------------------------------------------
__global__ __launch_bounds__(256) void k4_final(
        const float* __restrict__ queries, const float* __restrict__ G,
        const float* __restrict__ bo, float* __restrict__ outp) {
    const int b  = blockIdx.x >> 7;
    const int r0 = (blockIdx.x & 127) * 128;

    __shared__ short Gt[128 * 136];   // Gt[c][c'] = G[c'][c] * invN  (B-layout)
    {
        const float* Gb = G + (size_t)b * DD * DD;
        const float invN = 6.103515625e-05f;  // 1/16384
#pragma unroll 4
        for (int it = 0; it < 64; ++it) {
            const int idx = threadIdx.x + it * 256;
            const int cp = idx >> 7, c = idx & 127;
            Gt[c * 136 + cp] = f2bf(Gb[idx] * invN);
        }
    }
    __syncthreads();

    const int lane = threadIdx.x & 63;
    const int w    = threadIdx.x >> 6;
    const int ml   = lane & 15;
    const int quad = lane >> 4;
    const float* qbase = queries + ((size_t)b * NN + r0) * DD;

    f32x4 acc[2][8];
#pragma unroll
    for (int i = 0; i < 2; ++i)
#pragma unroll
        for (int t = 0; t < 8; ++t) acc[i][t] = (f32x4){0.f, 0.f, 0.f, 0.f};

#pragma unroll
    for (int kc = 0; kc < 4; ++kc) {
        const int k0 = kc * 32 + quad * 8;
        bf16x8 a[2];
#pragma unroll
        for (int i = 0; i < 2; ++i)
            a[i] = load_row8(qbase + (size_t)((2 * w + i) * 16 + ml) * DD + k0);
#pragma unroll
        for (int t = 0; t < 8; ++t) {
            bf16x8 bf = *(const bf16x8*)&Gt[(t * 16 + ml) * 136 + k0];
            acc[0][t] = MFMA(a[0], bf, acc[0][t]);
            acc[1][t] = MFMA(a[1], bf, acc[1][t]);
        }
    }

    float* ob = outp + ((size_t)b * NN + r0) * DD;
#pragma unroll
    for (int t = 0; t < 8; ++t) {
        const int c = t * 16 + ml;
        const float boc = bo[c];
#pragma unroll
        for (int i = 0; i < 2; ++i)
#pragma unroll
            for (int r = 0; r < 4; ++r)
                ob[(size_t)((2 * w + i) * 16 + quad * 4 + r) * DD + c] =
                    acc[i][t][r] + boc;
    }
}

extern "C" void kernel_launch(void* const* d_in, const int* in_sizes, int n_in,
                              void* d_out, int out_size, void* d_ws, size_t ws_size,
                              hipStream_t stream) {
    const float* queries = (const float*)d_in[0];
    const float* keys    = (const float*)d_in[1];
    const float* values  = (const float*)d_in[2];
    const float* Wq      = (const float*)d_in[3];
    const float* Wk      = (const float*)d_in[4];
    const float* Wo      = (const float*)d_in[5];
    const float* bo      = (const float*)d_in[6];
    float* out = (float*)d_out;

    // ws layout: [B*PC partial S (128x128 f32)] [S: B*128*128 f32] [G: same]
    int PC = 64;
    while (PC > 1 &&
           (size_t)BB * PC * DD * DD * 4 + 2 * (size_t)BB * DD * DD * 4 > ws_size)
        PC >>= 1;
    float* partial = (float*)d_ws;
    float* S = partial + (size_t)BB * PC * DD * DD;
    float* G = S + (size_t)BB * DD * DD;
    const int rows = NN / PC;

    hipLaunchKernelGGL(k1_partialS, dim3(BB * PC), dim3(512), 0, stream,
                       keys, values, partial, PC, rows);
    hipLaunchKernelGGL(k2_reduce, dim3(64), dim3(256), 0, stream,
                       partial, S, G, PC);
    hipLaunchKernelGGL(k3_middle, dim3(BB * HH), dim3(256), 0, stream,
                       S, Wq, Wk, Wo, G);
    hipLaunchKernelGGL(k4_final, dim3(512), dim3(256), 0, stream,
                       queries, G, bo, out);
}

// Round 2
// 178.679 us; speedup vs baseline: 1.1207x; 1.1207x over previous
//
#include <hip/hip_runtime.h>
#include <hip/hip_bf16.h>

#define BB    4
#define NN    16384
#define DD    128
#define HH    8
#define DHH   64
#define INNER 512
#define PC    64          // K^T V row-chunks per batch (grid K1 = BB*PC = 256)

typedef __attribute__((ext_vector_type(8))) short bf16x8;
typedef __attribute__((ext_vector_type(4))) float f32x4;
typedef unsigned short ushort_t;

#define MFMA(a, b, c) __builtin_amdgcn_mfma_f32_16x16x32_bf16((a), (b), (c), 0, 0, 0)

// fp32 -> bf16 round-to-nearest-even
__device__ __forceinline__ short f2bf(float x) {
    union { float f; unsigned u; } v; v.f = x;
    unsigned u = v.u;
    u += 0x7fffu + ((u >> 16) & 1u);
    return (short)(u >> 16);
}

__device__ __forceinline__ float bf2f(ushort_t us) {
    union { unsigned u; float f; } v;
    v.u = ((unsigned)us) << 16;
    return v.f;
}

// 8 consecutive floats at p -> bf16x8 (A-row / B-row fragment)
__device__ __forceinline__ bf16x8 load_row8(const float* __restrict__ p) {
    f32x4 a = *(const f32x4*)p;
    f32x4 b = *(const f32x4*)(p + 4);
    bf16x8 r;
    r[0] = f2bf(a[0]); r[1] = f2bf(a[1]); r[2] = f2bf(a[2]); r[3] = f2bf(a[3]);
    r[4] = f2bf(b[0]); r[5] = f2bf(b[1]); r[6] = f2bf(b[2]); r[7] = f2bf(b[3]);
    return r;
}

// 8 floats strided by `stride` elements -> bf16x8 (column fragment)
__device__ __forceinline__ bf16x8 load_col8(const float* __restrict__ p, int stride) {
    bf16x8 r;
#pragma unroll
    for (int j = 0; j < 8; ++j) r[j] = f2bf(p[(size_t)j * stride]);
    return r;
}

// ---------------------------------------------------------------------------
// K1: partial S[b] = keys[b]^T @ values[b] over a 256-row chunk; bf16 out.
// Grid: BB*PC=256 blocks x 512 threads (8 waves as 4x2 m x n wave-grid:
// each wave owns 2 m-tiles x 4 n-tiles -> 48 scalar loads/iter, V re-read
// 4x (L1-absorbed) instead of 8x).
// ---------------------------------------------------------------------------
__global__ __launch_bounds__(512) void k1_partialS(
        const float* __restrict__ keys, const float* __restrict__ vals,
        ushort_t* __restrict__ partial) {
    const int b     = blockIdx.x >> 6;       // /PC
    const int chunk = blockIdx.x & (PC - 1);
    const int r0    = chunk * (NN / PC);     // 256 rows per chunk
    const int lane  = threadIdx.x & 63;
    const int w     = threadIdx.x >> 6;      // 0..7
    const int mw    = w & 3;                 // m wave-coord (2 m-tiles each)
    const int nw    = w >> 2;                // n wave-coord (4 n-tiles each)
    const int ml    = lane & 15;
    const int quad  = lane >> 4;

    const float* kbase = keys + (size_t)b * NN * DD;
    const float* vbase = vals + (size_t)b * NN * DD;

    f32x4 acc[2][4];
#pragma unroll
    for (int i = 0; i < 2; ++i)
#pragma unroll
        for (int t = 0; t < 4; ++t) acc[i][t] = (f32x4){0.f, 0.f, 0.f, 0.f};

    for (int n0 = r0; n0 < r0 + (NN / PC); n0 += 32) {
        const int nbase = n0 + quad * 8;
        // A = K^T: lane holds col d = (2mw+i)*16+ml of K rows nbase..+7
        bf16x8 a[2];
#pragma unroll
        for (int i = 0; i < 2; ++i)
            a[i] = load_col8(kbase + (size_t)nbase * DD + (2 * mw + i) * 16 + ml, DD);
#pragma unroll
        for (int t = 0; t < 4; ++t) {
            const int e = (nw * 4 + t) * 16 + ml;
            bf16x8 bf = load_col8(vbase + (size_t)nbase * DD + e, DD);
            acc[0][t] = MFMA(a[0], bf, acc[0][t]);
            acc[1][t] = MFMA(a[1], bf, acc[1][t]);
        }
    }
    // C layout: row = m-tile*16 + quad*4 + r, col = n-tile*16 + ml
    ushort_t* outp = partial + (size_t)blockIdx.x * DD * DD;
#pragma unroll
    for (int i = 0; i < 2; ++i) {
        const int mrow = (2 * mw + i) * 16 + quad * 4;
#pragma unroll
        for (int t = 0; t < 4; ++t) {
            const int col = (nw * 4 + t) * 16 + ml;
#pragma unroll
            for (int r = 0; r < 4; ++r)
                outp[(size_t)(mrow + r) * DD + col] = (ushort_t)f2bf(acc[i][t][r]);
        }
    }
}

// ---------------------------------------------------------------------------
// K2: S[b] = sum of PC bf16 partials (fp32 accum); also zero G.
// Grid: 256 blocks x 256 threads — one output element per thread, full-CU.
// ---------------------------------------------------------------------------
__global__ __launch_bounds__(256) void k2_reduce(
        const ushort_t* __restrict__ partial, float* __restrict__ S,
        float* __restrict__ G) {
    const int t   = blockIdx.x * 256 + threadIdx.x;  // 0..65535
    const int b   = t >> 14;
    const int idx = t & 16383;
    const ushort_t* p = partial + ((size_t)b * PC) * DD * DD + idx;
    float s = 0.f;
#pragma unroll 16
    for (int c = 0; c < PC; ++c) s += bf2f(p[(size_t)c * DD * DD]);
    S[t] = s;
    G[t] = 0.f;
}

// ---------------------------------------------------------------------------
// K3: middle chain per (b,h):
//   T1 = Wk_h @ S[b]          (64x128, K=128)
//   dots = T1 @ Wk_h^T        (64x64,  K=128)
//   T2 = Wq_h^T @ dots        (128x64, K=64)
//   C3 = T2 @ Wo_h^T          (128x128,K=64)  -> atomicAdd into G[b]
// s1 waves own n-tiles so S[b] is read exactly once per block.
// ---------------------------------------------------------------------------
__global__ __launch_bounds__(256) void k3_middle(
        const float* __restrict__ S, const float* __restrict__ Wq,
        const float* __restrict__ Wk, const float* __restrict__ Wo,
        float* __restrict__ G) {
    const int b    = blockIdx.x >> 3;
    const int h    = blockIdx.x & 7;
    const int lane = threadIdx.x & 63;
    const int w    = threadIdx.x >> 6;   // 0..3
    const int ml   = lane & 15;
    const int quad = lane >> 4;

    __shared__ short lds[22528];
    short* T1 = lds;            // [64][136]  A-layout rows d, cols c'
    short* dT = lds + 8704;     // [64][72]   dots^T: [e][d] (B-layout for T2)
    short* T2 = lds + 13312;    // [128][72]  A-layout rows c', cols e

    const float* Sb  = S  + (size_t)b * DD * DD;
    const float* Wkh = Wk + (size_t)h * DHH * DD;   // Wk[(h*64+d)*128 + c]
    const float* Wqh = Wq + (size_t)h * DHH * DD;

    // s1: T1 = Wk_h @ S[b].  wave w -> n-tiles {2w,2w+1}, all 4 m-tiles.
    {
        f32x4 acc[4][2];
#pragma unroll
        for (int mi = 0; mi < 4; ++mi)
#pragma unroll
            for (int j = 0; j < 2; ++j) acc[mi][j] = (f32x4){0.f, 0.f, 0.f, 0.f};
#pragma unroll
        for (int kc = 0; kc < 4; ++kc) {
            const int c0 = kc * 32 + quad * 8;
            bf16x8 a[4];
#pragma unroll
            for (int mi = 0; mi < 4; ++mi)
                a[mi] = load_row8(Wkh + (size_t)(mi * 16 + ml) * DD + c0);
#pragma unroll
            for (int j = 0; j < 2; ++j) {
                // B[k=c][n=c'] = S[c][c']: column of S, stride 128
                bf16x8 bf = load_col8(Sb + (size_t)c0 * DD + (2 * w + j) * 16 + ml, DD);
#pragma unroll
                for (int mi = 0; mi < 4; ++mi)
                    acc[mi][j] = MFMA(a[mi], bf, acc[mi][j]);
            }
        }
#pragma unroll
        for (int mi = 0; mi < 4; ++mi)
#pragma unroll
            for (int j = 0; j < 2; ++j)
#pragma unroll
                for (int r = 0; r < 4; ++r)
                    T1[(mi * 16 + quad * 4 + r) * 136 + (2 * w + j) * 16 + ml] =
                        f2bf(acc[mi][j][r]);
    }
    __syncthreads();

    // s2: dots = T1 @ Wk_h^T.  wave w -> m-tile w, 4 n-tiles.
    {
        f32x4 acc[4];
#pragma unroll
        for (int t = 0; t < 4; ++t) acc[t] = (f32x4){0.f, 0.f, 0.f, 0.f};
#pragma unroll
        for (int kc = 0; kc < 4; ++kc) {
            const int c0 = kc * 32 + quad * 8;
            bf16x8 a = *(const bf16x8*)&T1[(w * 16 + ml) * 136 + c0];
#pragma unroll
            for (int t = 0; t < 4; ++t) {
                // B[k=c'][n=e] = Wk_h[e][c'] : row of Wk, contiguous
                bf16x8 bf = load_row8(Wkh + (size_t)(t * 16 + ml) * DD + c0);
                acc[t] = MFMA(a, bf, acc[t]);
            }
        }
        // store transposed: dT[e][d]
#pragma unroll
        for (int t = 0; t < 4; ++t)
#pragma unroll
            for (int r = 0; r < 4; ++r)
                dT[(t * 16 + ml) * 72 + w * 16 + quad * 4 + r] = f2bf(acc[t][r]);
    }
    __syncthreads();

    // s3: T2 = Wq_h^T @ dots.  wave w -> m-tiles 2w,2w+1; 4 n-tiles; kc 0..1.
    {
        f32x4 acc[2][4];
#pragma unroll
        for (int i = 0; i < 2; ++i)
#pragma unroll
            for (int t = 0; t < 4; ++t) acc[i][t] = (f32x4){0.f, 0.f, 0.f, 0.f};
#pragma unroll
        for (int kc = 0; kc < 2; ++kc) {
            const int d0 = kc * 32 + quad * 8;
            bf16x8 a[2];
#pragma unroll
            for (int i = 0; i < 2; ++i) {
                const int cp = (2 * w + i) * 16 + ml;  // m = c'
                // A[m=c'][k=d] = Wq[(h64+d)][c'] : column, stride 128
                a[i] = load_col8(Wqh + (size_t)d0 * DD + cp, DD);
            }
#pragma unroll
            for (int t = 0; t < 4; ++t) {
                bf16x8 bf = *(const bf16x8*)&dT[(t * 16 + ml) * 72 + d0];
                acc[0][t] = MFMA(a[0], bf, acc[0][t]);
                acc[1][t] = MFMA(a[1], bf, acc[1][t]);
            }
        }
#pragma unroll
        for (int i = 0; i < 2; ++i)
#pragma unroll
            for (int t = 0; t < 4; ++t)
#pragma unroll
                for (int r = 0; r < 4; ++r)
                    T2[((2 * w + i) * 16 + quad * 4 + r) * 72 + t * 16 + ml] =
                        f2bf(acc[i][t][r]);
    }
    __syncthreads();

    // s4: C3 = T2 @ Wo_h^T -> atomicAdd G[b].  2 m-tiles, 8 n-tiles, kc 0..1.
    {
        f32x4 acc[2][8];
#pragma unroll
        for (int i = 0; i < 2; ++i)
#pragma unroll
            for (int t = 0; t < 8; ++t) acc[i][t] = (f32x4){0.f, 0.f, 0.f, 0.f};
#pragma unroll
        for (int kc = 0; kc < 2; ++kc) {
            const int e0 = kc * 32 + quad * 8;
            bf16x8 a[2];
#pragma unroll
            for (int i = 0; i < 2; ++i)
                a[i] = *(const bf16x8*)&T2[((2 * w + i) * 16 + ml) * 72 + e0];
#pragma unroll
            for (int t = 0; t < 8; ++t) {
                // B[k=e][n=c] = Wo[c][h64+e] : row of Wo, contiguous
                bf16x8 bf = load_row8(Wo + (size_t)(t * 16 + ml) * INNER + h * DHH + e0);
                acc[0][t] = MFMA(a[0], bf, acc[0][t]);
                acc[1][t] = MFMA(a[1], bf, acc[1][t]);
            }
        }
        float* Gb = G + (size_t)b * DD * DD;
#pragma unroll
        for (int i = 0; i < 2; ++i)
#pragma unroll
            for (int t = 0; t < 8; ++t)
#pragma unroll
                for (int r = 0; r < 4; ++r)
                    atomicAdd(&Gb[((2 * w + i) * 16 + quad * 4 + r) * DD + t * 16 + ml],
                              acc[i][t][r]);
    }
}

// ---------------------------------------------------------------------------
// K4: out[b] = queries[b] @ (G[b]/N) + bo.
// Grid: 512 blocks x 256 threads; block covers 128 rows. G staged to LDS
// transposed+scaled (1/N = 2^-14 exact). A-frags direct from global.
// ---------------------------------------------------------------------------
__global__ __launch_bounds__(256) void k4_final(
        const float* __restrict__ queries, const float* __restrict__ G,
        const float* __restrict__ bo, float* __restrict__ outp) {
    const int b  = blockIdx.x >> 7;
    const int r0 = (blockIdx.x & 127) * 128;

    __shared__ short Gt[128 * 136];   // Gt[c][c'] = G[c'][c] * invN  (B-layout)
    {
        const float* Gb = G + (size_t)b * DD * DD;
        const float invN = 6.103515625e-05f;  // 1/16384
#pragma unroll 4
        for (int it = 0; it < 64; ++it) {
            const int idx = threadIdx.x + it * 256;
            const int cp = idx >> 7, c = idx & 127;
            Gt[c * 136 + cp] = f2bf(Gb[idx] * invN);
        }
    }
    __syncthreads();

    const int lane = threadIdx.x & 63;
    const int w    = threadIdx.x >> 6;
    const int ml   = lane & 15;
    const int quad = lane >> 4;
    const float* qbase = queries + ((size_t)b * NN + r0) * DD;

    f32x4 acc[2][8];
#pragma unroll
    for (int i = 0; i < 2; ++i)
#pragma unroll
        for (int t = 0; t < 8; ++t) acc[i][t] = (f32x4){0.f, 0.f, 0.f, 0.f};

#pragma unroll
    for (int kc = 0; kc < 4; ++kc) {
        const int k0 = kc * 32 + quad * 8;
        bf16x8 a[2];
#pragma unroll
        for (int i = 0; i < 2; ++i)
            a[i] = load_row8(qbase + (size_t)((2 * w + i) * 16 + ml) * DD + k0);
#pragma unroll
        for (int t = 0; t < 8; ++t) {
            bf16x8 bf = *(const bf16x8*)&Gt[(t * 16 + ml) * 136 + k0];
            acc[0][t] = MFMA(a[0], bf, acc[0][t]);
            acc[1][t] = MFMA(a[1], bf, acc[1][t]);
        }
    }

    float* ob = outp + ((size_t)b * NN + r0) * DD;
#pragma unroll
    for (int t = 0; t < 8; ++t) {
        const int c = t * 16 + ml;
        const float boc = bo[c];
#pragma unroll
        for (int i = 0; i < 2; ++i)
#pragma unroll
            for (int r = 0; r < 4; ++r)
                ob[(size_t)((2 * w + i) * 16 + quad * 4 + r) * DD + c] =
                    acc[i][t][r] + boc;
    }
}

extern "C" void kernel_launch(void* const* d_in, const int* in_sizes, int n_in,
                              void* d_out, int out_size, void* d_ws, size_t ws_size,
                              hipStream_t stream) {
    const float* queries = (const float*)d_in[0];
    const float* keys    = (const float*)d_in[1];
    const float* values  = (const float*)d_in[2];
    const float* Wq      = (const float*)d_in[3];
    const float* Wk      = (const float*)d_in[4];
    const float* Wo      = (const float*)d_in[5];
    const float* bo      = (const float*)d_in[6];
    float* out = (float*)d_out;

    // ws layout: [S: B*128*128 f32][G: B*128*128 f32][partial: B*PC*128*128 bf16]
    float* S = (float*)d_ws;
    float* G = S + (size_t)BB * DD * DD;
    ushort_t* partial = (ushort_t*)(G + (size_t)BB * DD * DD);

    hipLaunchKernelGGL(k1_partialS, dim3(BB * PC), dim3(512), 0, stream,
                       keys, values, partial);
    hipLaunchKernelGGL(k2_reduce, dim3(256), dim3(256), 0, stream,
                       partial, S, G);
    hipLaunchKernelGGL(k3_middle, dim3(BB * HH), dim3(256), 0, stream,
                       S, Wq, Wk, Wo, G);
    hipLaunchKernelGGL(k4_final, dim3(512), dim3(256), 0, stream,
                       queries, G, bo, out);
}

// Round 3
// 177.025 us; speedup vs baseline: 1.1311x; 1.0093x over previous
//
#include <hip/hip_runtime.h>
#include <hip/hip_bf16.h>

#define BB    4
#define NN    16384
#define DD    128
#define HH    8
#define DHH   64
#define INNER 512
#define PC    64          // K^T V row-chunks per batch (K1 main grid = BB*PC = 256)

typedef __attribute__((ext_vector_type(8))) short bf16x8;
typedef __attribute__((ext_vector_type(4))) float f32x4;
typedef unsigned short ushort_t;

#define MFMA(a, b, c) __builtin_amdgcn_mfma_f32_16x16x32_bf16((a), (b), (c), 0, 0, 0)

// fp32 -> bf16 round-to-nearest-even
__device__ __forceinline__ short f2bf(float x) {
    union { float f; unsigned u; } v; v.f = x;
    unsigned u = v.u;
    u += 0x7fffu + ((u >> 16) & 1u);
    return (short)(u >> 16);
}

__device__ __forceinline__ float bf2f(ushort_t us) {
    union { unsigned u; float f; } v;
    v.u = ((unsigned)us) << 16;
    return v.f;
}

// 8 consecutive floats at p -> bf16x8 (A-row / B-row fragment)
__device__ __forceinline__ bf16x8 load_row8(const float* __restrict__ p) {
    f32x4 a = *(const f32x4*)p;
    f32x4 b = *(const f32x4*)(p + 4);
    bf16x8 r;
    r[0] = f2bf(a[0]); r[1] = f2bf(a[1]); r[2] = f2bf(a[2]); r[3] = f2bf(a[3]);
    r[4] = f2bf(b[0]); r[5] = f2bf(b[1]); r[6] = f2bf(b[2]); r[7] = f2bf(b[3]);
    return r;
}

// 8 floats strided by `stride` elements -> bf16x8 (column fragment)
__device__ __forceinline__ bf16x8 load_col8(const float* __restrict__ p, int stride) {
    bf16x8 r;
#pragma unroll
    for (int j = 0; j < 8; ++j) r[j] = f2bf(p[(size_t)j * stride]);
    return r;
}

// ---------------------------------------------------------------------------
// K1: blocks [0,256): partial S[b] = keys[b]^T @ values[b] over a 256-row
// chunk, bf16 out (unchanged from R2 — BW-bound at ~11-12us).
// Blocks [256,272): head-factor producers, riding along for free:
//   A_h  = Wq_h^T @ Wk_h            (128x128, K=64)   -> Abf  row-major [c'][c]
//   B'_h = Wk_h^T @ Wo_h^T, stored transposed: BT[cout][cin] (K=64)
// These depend only on weights, so they overlap K1's memory-bound phase.
// ---------------------------------------------------------------------------
__global__ __launch_bounds__(512) void k1_partialS_ab(
        const float* __restrict__ keys, const float* __restrict__ vals,
        const float* __restrict__ Wq, const float* __restrict__ Wk,
        const float* __restrict__ Wo,
        ushort_t* __restrict__ partial, ushort_t* __restrict__ Abf,
        ushort_t* __restrict__ BTbf) {
    const int lane = threadIdx.x & 63;
    const int w    = threadIdx.x >> 6;   // 0..7
    const int ml   = lane & 15;
    const int quad = lane >> 4;

    if (blockIdx.x < BB * PC) {
        // ---- partial S ----
        const int b     = blockIdx.x >> 6;
        const int chunk = blockIdx.x & (PC - 1);
        const int r0    = chunk * (NN / PC);
        const int mw    = w & 3;
        const int nw    = w >> 2;

        const float* kbase = keys + (size_t)b * NN * DD;
        const float* vbase = vals + (size_t)b * NN * DD;

        f32x4 acc[2][4];
#pragma unroll
        for (int i = 0; i < 2; ++i)
#pragma unroll
            for (int t = 0; t < 4; ++t) acc[i][t] = (f32x4){0.f, 0.f, 0.f, 0.f};

        for (int n0 = r0; n0 < r0 + (NN / PC); n0 += 32) {
            const int nbase = n0 + quad * 8;
            bf16x8 a[2];
#pragma unroll
            for (int i = 0; i < 2; ++i)
                a[i] = load_col8(kbase + (size_t)nbase * DD + (2 * mw + i) * 16 + ml, DD);
#pragma unroll
            for (int t = 0; t < 4; ++t) {
                const int e = (nw * 4 + t) * 16 + ml;
                bf16x8 bf = load_col8(vbase + (size_t)nbase * DD + e, DD);
                acc[0][t] = MFMA(a[0], bf, acc[0][t]);
                acc[1][t] = MFMA(a[1], bf, acc[1][t]);
            }
        }
        ushort_t* outp = partial + (size_t)blockIdx.x * DD * DD;
#pragma unroll
        for (int i = 0; i < 2; ++i) {
            const int mrow = (2 * mw + i) * 16 + quad * 4;
#pragma unroll
            for (int t = 0; t < 4; ++t) {
                const int col = (nw * 4 + t) * 16 + ml;
#pragma unroll
                for (int r = 0; r < 4; ++r)
                    outp[(size_t)(mrow + r) * DD + col] = (ushort_t)f2bf(acc[i][t][r]);
            }
        }
    } else {
        // ---- head-factor producer ----
        const int ab    = blockIdx.x - BB * PC;   // 0..15
        const int h     = ab & 7;
        const int which = ab >> 3;                // 0 -> A_h, 1 -> BT_h
        const float* Wkh = Wk + (size_t)h * DHH * DD;

        f32x4 acc[8];
#pragma unroll
        for (int t = 0; t < 8; ++t) acc[t] = (f32x4){0.f, 0.f, 0.f, 0.f};

        if (which == 0) {
            // A_h[c'][c] = sum_d Wq[h64+d][c'] * Wk[h64+d][c]; m=c', n=c, k=d
            const float* Wqh = Wq + (size_t)h * DHH * DD;
#pragma unroll
            for (int kc = 0; kc < 2; ++kc) {
                const int d0 = kc * 32 + quad * 8;
                bf16x8 a = load_col8(Wqh + (size_t)d0 * DD + w * 16 + ml, DD);
#pragma unroll
                for (int t = 0; t < 8; ++t) {
                    bf16x8 bf = load_col8(Wkh + (size_t)d0 * DD + t * 16 + ml, DD);
                    acc[t] = MFMA(a, bf, acc[t]);
                }
            }
            ushort_t* dst = Abf + (size_t)h * DD * DD;
#pragma unroll
            for (int t = 0; t < 8; ++t)
#pragma unroll
                for (int r = 0; r < 4; ++r)
                    dst[(size_t)(w * 16 + quad * 4 + r) * DD + t * 16 + ml] =
                        (ushort_t)f2bf(acc[t][r]);
        } else {
            // B'_h[cin][cout] = sum_e Wk[h64+e][cin] * Wo[cout][h64+e]
            // computed with m=cout, n=cin -> stored BT[cout][cin]
#pragma unroll
            for (int kc = 0; kc < 2; ++kc) {
                const int e0 = kc * 32 + quad * 8;
                bf16x8 a = load_row8(Wo + (size_t)(w * 16 + ml) * INNER + h * DHH + e0);
#pragma unroll
                for (int t = 0; t < 8; ++t) {
                    bf16x8 bf = load_col8(Wkh + (size_t)e0 * DD + t * 16 + ml, DD);
                    acc[t] = MFMA(a, bf, acc[t]);
                }
            }
            ushort_t* dst = BTbf + (size_t)h * DD * DD;
#pragma unroll
            for (int t = 0; t < 8; ++t)
#pragma unroll
                for (int r = 0; r < 4; ++r)
                    dst[(size_t)(w * 16 + quad * 4 + r) * DD + t * 16 + ml] =
                        (ushort_t)f2bf(acc[t][r]);
        }
    }
}

// ---------------------------------------------------------------------------
// K2: S[b] = sum of PC bf16 partials (fp32 accum); also zero G.
// Grid: 256 blocks x 256 threads — one output element per thread.
// ---------------------------------------------------------------------------
__global__ __launch_bounds__(256) void k2_reduce(
        const ushort_t* __restrict__ partial, float* __restrict__ S,
        float* __restrict__ G) {
    const int t   = blockIdx.x * 256 + threadIdx.x;  // 0..65535
    const int b   = t >> 14;
    const int idx = t & 16383;
    const ushort_t* p = partial + ((size_t)b * PC) * DD * DD + idx;
    float s = 0.f;
#pragma unroll 16
    for (int c = 0; c < PC; ++c) s += bf2f(p[(size_t)c * DD * DD]);
    S[t] = s;
    G[t] = 0.f;
}

// ---------------------------------------------------------------------------
// K3: G[b] += A_h @ S[b] @ B'_h per (b,h) — two dependent stages only.
//   stage1: T = A_h @ S[b]      (128x128, K=128)  -> LDS bf16 A-layout
//   stage2: G += T @ B'_h       (128x128, K=128)  -> fp32 atomicAdd
// Grid: 32 blocks x 256 threads.
// ---------------------------------------------------------------------------
__global__ __launch_bounds__(256) void k3_middle(
        const float* __restrict__ S, const ushort_t* __restrict__ Abf,
        const ushort_t* __restrict__ BTbf, float* __restrict__ G) {
    const int b    = blockIdx.x >> 3;
    const int h    = blockIdx.x & 7;
    const int lane = threadIdx.x & 63;
    const int w    = threadIdx.x >> 6;   // 0..3
    const int ml   = lane & 15;
    const int quad = lane >> 4;

    __shared__ short T[128 * 136];       // T[c'][c''] A-layout, pitch 136

    const float*    Sb = S    + (size_t)b * DD * DD;
    const ushort_t* Ah = Abf  + (size_t)h * DD * DD;
    const ushort_t* Bh = BTbf + (size_t)h * DD * DD;

    // stage1: T = A_h @ S[b]. wave w -> m-tiles {2w,2w+1} x 8 n-tiles.
    {
        f32x4 acc[2][8];
#pragma unroll
        for (int i = 0; i < 2; ++i)
#pragma unroll
            for (int t = 0; t < 8; ++t) acc[i][t] = (f32x4){0.f, 0.f, 0.f, 0.f};
#pragma unroll
        for (int kc = 0; kc < 4; ++kc) {
            const int c0 = kc * 32 + quad * 8;
            bf16x8 a[2];
#pragma unroll
            for (int i = 0; i < 2; ++i)
                a[i] = *(const bf16x8*)&Ah[(size_t)((2 * w + i) * 16 + ml) * DD + c0];
#pragma unroll
            for (int t = 0; t < 8; ++t) {
                // B[k=c][n=c''] = S[c][c'']: column of S, stride 128
                bf16x8 bf = load_col8(Sb + (size_t)c0 * DD + t * 16 + ml, DD);
                acc[0][t] = MFMA(a[0], bf, acc[0][t]);
                acc[1][t] = MFMA(a[1], bf, acc[1][t]);
            }
        }
#pragma unroll
        for (int i = 0; i < 2; ++i)
#pragma unroll
            for (int t = 0; t < 8; ++t)
#pragma unroll
                for (int r = 0; r < 4; ++r)
                    T[((2 * w + i) * 16 + quad * 4 + r) * 136 + t * 16 + ml] =
                        f2bf(acc[i][t][r]);
    }
    __syncthreads();

    // stage2: G += T @ B'_h.  B[k=cin][n=cout] = BT[cout][cin] rows.
    {
        f32x4 acc[2][8];
#pragma unroll
        for (int i = 0; i < 2; ++i)
#pragma unroll
            for (int t = 0; t < 8; ++t) acc[i][t] = (f32x4){0.f, 0.f, 0.f, 0.f};
#pragma unroll
        for (int kc = 0; kc < 4; ++kc) {
            const int k0 = kc * 32 + quad * 8;
            bf16x8 a[2];
#pragma unroll
            for (int i = 0; i < 2; ++i)
                a[i] = *(const bf16x8*)&T[((2 * w + i) * 16 + ml) * 136 + k0];
#pragma unroll
            for (int t = 0; t < 8; ++t) {
                bf16x8 bf = *(const bf16x8*)&Bh[(size_t)(t * 16 + ml) * DD + k0];
                acc[0][t] = MFMA(a[0], bf, acc[0][t]);
                acc[1][t] = MFMA(a[1], bf, acc[1][t]);
            }
        }
        float* Gb = G + (size_t)b * DD * DD;
#pragma unroll
        for (int i = 0; i < 2; ++i)
#pragma unroll
            for (int t = 0; t < 8; ++t)
#pragma unroll
                for (int r = 0; r < 4; ++r)
                    atomicAdd(&Gb[((2 * w + i) * 16 + quad * 4 + r) * DD + t * 16 + ml],
                              acc[i][t][r]);
    }
}

// ---------------------------------------------------------------------------
// K4: out[b] = queries[b] @ (G[b]/N) + bo.
// Grid: 256 blocks x 512 threads; block covers 256 rows (one Gt staging per
// 256 rows). G staged to LDS transposed+scaled (1/N = 2^-14 exact).
// ---------------------------------------------------------------------------
__global__ __launch_bounds__(512) void k4_final(
        const float* __restrict__ queries, const float* __restrict__ G,
        const float* __restrict__ bo, float* __restrict__ outp) {
    const int b  = blockIdx.x >> 6;
    const int r0 = (blockIdx.x & 63) * 256;

    __shared__ short Gt[128 * 136];   // Gt[c][c'] = G[c'][c] * invN  (B-layout)
    {
        const float* Gb = G + (size_t)b * DD * DD;
        const float invN = 6.103515625e-05f;  // 1/16384
#pragma unroll 4
        for (int it = 0; it < 32; ++it) {
            const int idx = threadIdx.x + it * 512;
            const int cp = idx >> 7, c = idx & 127;
            Gt[c * 136 + cp] = f2bf(Gb[idx] * invN);
        }
    }
    __syncthreads();

    const int lane = threadIdx.x & 63;
    const int w    = threadIdx.x >> 6;   // 0..7 -> row tiles {2w, 2w+1}
    const int ml   = lane & 15;
    const int quad = lane >> 4;
    const float* qbase = queries + ((size_t)b * NN + r0) * DD;

    f32x4 acc[2][8];
#pragma unroll
    for (int i = 0; i < 2; ++i)
#pragma unroll
        for (int t = 0; t < 8; ++t) acc[i][t] = (f32x4){0.f, 0.f, 0.f, 0.f};

#pragma unroll
    for (int kc = 0; kc < 4; ++kc) {
        const int k0 = kc * 32 + quad * 8;
        bf16x8 a[2];
#pragma unroll
        for (int i = 0; i < 2; ++i)
            a[i] = load_row8(qbase + (size_t)((2 * w + i) * 16 + ml) * DD + k0);
#pragma unroll
        for (int t = 0; t < 8; ++t) {
            bf16x8 bf = *(const bf16x8*)&Gt[(t * 16 + ml) * 136 + k0];
            acc[0][t] = MFMA(a[0], bf, acc[0][t]);
            acc[1][t] = MFMA(a[1], bf, acc[1][t]);
        }
    }

    float* ob = outp + ((size_t)b * NN + r0) * DD;
#pragma unroll
    for (int t = 0; t < 8; ++t) {
        const int c = t * 16 + ml;
        const float boc = bo[c];
#pragma unroll
        for (int i = 0; i < 2; ++i)
#pragma unroll
            for (int r = 0; r < 4; ++r)
                ob[(size_t)((2 * w + i) * 16 + quad * 4 + r) * DD + c] =
                    acc[i][t][r] + boc;
    }
}

extern "C" void kernel_launch(void* const* d_in, const int* in_sizes, int n_in,
                              void* d_out, int out_size, void* d_ws, size_t ws_size,
                              hipStream_t stream) {
    const float* queries = (const float*)d_in[0];
    const float* keys    = (const float*)d_in[1];
    const float* values  = (const float*)d_in[2];
    const float* Wq      = (const float*)d_in[3];
    const float* Wk      = (const float*)d_in[4];
    const float* Wo      = (const float*)d_in[5];
    const float* bo      = (const float*)d_in[6];
    float* out = (float*)d_out;

    // ws: [S f32][G f32][Abf bf16 x8][BTbf bf16 x8][partial bf16]
    float* S = (float*)d_ws;
    float* G = S + (size_t)BB * DD * DD;
    ushort_t* Abf     = (ushort_t*)(G + (size_t)BB * DD * DD);
    ushort_t* BTbf    = Abf  + (size_t)HH * DD * DD;
    ushort_t* partial = BTbf + (size_t)HH * DD * DD;

    hipLaunchKernelGGL(k1_partialS_ab, dim3(BB * PC + 16), dim3(512), 0, stream,
                       keys, values, Wq, Wk, Wo, partial, Abf, BTbf);
    hipLaunchKernelGGL(k2_reduce, dim3(256), dim3(256), 0, stream,
                       partial, S, G);
    hipLaunchKernelGGL(k3_middle, dim3(BB * HH), dim3(256), 0, stream,
                       S, Abf, BTbf, G);
    hipLaunchKernelGGL(k4_final, dim3(256), dim3(512), 0, stream,
                       queries, G, bo, out);
}